// Round 6
// baseline (215.228 us; speedup 1.0000x reference)
//
#include <hip/hip_runtime.h>
#include <hip/hip_bf16.h>
#include <stdint.h>

#define Bb 8
#define Ss 1024
#define Dd 768
#define Hh 12
#define DH 64

typedef __attribute__((ext_vector_type(8))) short bf16x8;
typedef __attribute__((ext_vector_type(4))) float f32x4;

static __device__ __forceinline__ unsigned short f2b(float x) {
    union { float f; unsigned u; } v; v.f = x;
    unsigned r = v.u + 0x7FFFu + ((v.u >> 16) & 1u);
    return (unsigned short)(r >> 16);
}

static __device__ __forceinline__ void gll16(const void* g, void* l) {
    __builtin_amdgcn_global_load_lds((const __attribute__((address_space(1))) void*)g,
                                     (__attribute__((address_space(3))) void*)l,
                                     16, 0, 0);
}

// ---------------- kernel 1: fused prep (cvt + twt + loss) ----------------
// bid < 6144            : hidden f32 -> bf16
// 6144 <= bid < 7872    : W transpose+cvt -> Wt[w][n][k]
// bid == 7872           : loss = LMBDA * H * sum(mask)
__global__ __launch_bounds__(256) void k_prep(
    const float* __restrict__ hs,
    const float* __restrict__ Wq, const float* __restrict__ Wk, const float* __restrict__ Wv,
    const float* __restrict__ mask,
    unsigned short* __restrict__ hb, unsigned short* __restrict__ Wt,
    float* __restrict__ loss_out) {
    __shared__ float tile[32][33];
    __shared__ float red[4];
    const int bid = blockIdx.x;
    const int tid = threadIdx.x;
    if (bid < 6144) {
        const int i = (bid * 256 + tid) * 4;
        const float4 v = *reinterpret_cast<const float4*>(hs + i);
        ushort4 o;
        o.x = f2b(v.x); o.y = f2b(v.y); o.z = f2b(v.z); o.w = f2b(v.w);
        *reinterpret_cast<ushort4*>(hb + i) = o;
    } else if (bid < 7872) {
        const int t = bid - 6144;
        const int w = t / 576, rem = t % 576;
        const int k0 = (rem / 24) * 32, n0 = (rem % 24) * 32;
        const float* W = (w == 0) ? Wq : (w == 1) ? Wk : Wv;
        const int c = tid & 31, r0 = tid >> 5;
        #pragma unroll
        for (int i = 0; i < 4; ++i)
            tile[r0 + i * 8][c] = W[(size_t)(k0 + r0 + i * 8) * Dd + n0 + c];
        __syncthreads();
        unsigned short* o = Wt + (size_t)w * Dd * Dd;
        #pragma unroll
        for (int i = 0; i < 4; ++i)
            o[(size_t)(n0 + r0 + i * 8) * Dd + k0 + c] = f2b(tile[c][r0 + i * 8]);
    } else {
        float s = 0.f;
        for (int i = tid; i < Bb * Ss; i += 256) s += mask[i];
        #pragma unroll
        for (int d = 1; d < 64; d <<= 1) s += __shfl_xor(s, d);
        const int lane = tid & 63, wv = tid >> 6;
        if (lane == 0) red[wv] = s;
        __syncthreads();
        if (tid == 0)
            loss_out[0] = 0.01f * 12.f * (red[0] + red[1] + red[2] + red[3]);
    }
}

// ---------------- kernel 2: QKV GEMM, 2-phase double-buffered + XCD swizzle ----------------
// Single grid over N=2304 (w = nt/6 is block-uniform since 768 = 6*128).
// XCD x owns m-rows [x*1024,(x+1)*1024): A-chunk 1.5MB + B 3.5MB ~ L2-resident.
__global__ __launch_bounds__(256) void k_qkv(
    const unsigned short* __restrict__ hb,   // [8192][768] bf16
    const unsigned short* __restrict__ Wt,   // [2304][768] bf16 (n,k)
    const float* __restrict__ bq, const float* __restrict__ bk, const float* __restrict__ bv,
    unsigned short* __restrict__ Qo, unsigned short* __restrict__ Ko,
    unsigned short* __restrict__ Vo) {
    __shared__ __align__(16) unsigned short Al[2][4096];
    __shared__ __align__(16) unsigned short Bl[2][4096];
    const int bid = blockIdx.x;                 // 0..1151
    const int x = bid & 7, local = bid >> 3;    // XCD chunking (bijective: 8*144)
    const int mt = x * 8 + (local & 7);         // 0..63
    const int nt = local >> 3;                  // 0..17
    const int m0 = mt * 128, n0 = nt * 128;
    const int w  = nt / 6;                      // block-uniform
    const int tid = threadIdx.x, lane = tid & 63, wv = tid >> 6;
    const int l15 = lane & 15, l4 = lane >> 4;
    const int wm = (wv >> 1) * 64, wn = (wv & 1) * 64;

    f32x4 acc[4][4];
    #pragma unroll
    for (int i = 0; i < 4; ++i)
        #pragma unroll
        for (int j = 0; j < 4; ++j)
            acc[i][j] = f32x4{0.f, 0.f, 0.f, 0.f};

    const int ldr = lane >> 2;        // 16 rows per gll
    const int ldc = (lane & 3) * 8;   // 4x16B per row

    #define STAGE(buf, kt)                                                              \
        {                                                                               \
            const int k0_ = (kt) * 32;                                                  \
            _Pragma("unroll")                                                           \
            for (int i_ = 0; i_ < 2; ++i_) {                                            \
                const int c_ = wv * 2 + i_;                                             \
                gll16(hb + (size_t)(m0 + c_ * 16 + ldr) * Dd + k0_ + ldc, &Al[buf][c_ * 512]); \
                gll16(Wt + (size_t)(n0 + c_ * 16 + ldr) * Dd + k0_ + ldc, &Bl[buf][c_ * 512]); \
            }                                                                           \
        }

    #define COMPUTE(buf)                                                                \
        {                                                                               \
            bf16x8 af_[4], bf_[4];                                                      \
            _Pragma("unroll")                                                           \
            for (int i_ = 0; i_ < 4; ++i_) {                                            \
                af_[i_] = *reinterpret_cast<const bf16x8*>(&Al[buf][(wm + i_ * 16 + l15) * 32 + l4 * 8]); \
                bf_[i_] = *reinterpret_cast<const bf16x8*>(&Bl[buf][(wn + i_ * 16 + l15) * 32 + l4 * 8]); \
            }                                                                           \
            _Pragma("unroll")                                                           \
            for (int i_ = 0; i_ < 4; ++i_)                                              \
                _Pragma("unroll")                                                       \
                for (int j_ = 0; j_ < 4; ++j_)                                          \
                    acc[i_][j_] = __builtin_amdgcn_mfma_f32_16x16x32_bf16(af_[i_], bf_[j_], acc[i_][j_], 0, 0, 0); \
        }

    STAGE(0, 0);
    __syncthreads();
    int buf = 0;
    for (int kt = 1; kt < Dd / 32; ++kt) {
        STAGE(buf ^ 1, kt);    // prefetch next tile (T3 minimum 2-phase)
        COMPUTE(buf);
        __syncthreads();       // drains this wave's vmcnt -> buf^1 ready
        buf ^= 1;
    }
    COMPUTE(buf);
    #undef STAGE
    #undef COMPUTE

    const float* bias = (w == 0) ? bq : (w == 1) ? bk : bv;
    if (w < 2) {
        unsigned short* O = (w == 0) ? Qo : Ko;
        #pragma unroll
        for (int j = 0; j < 4; ++j) {
            const int nL = n0 + wn + j * 16 + l15 - w * Dd;
            const float bs = bias[nL];
            const int hh = nL >> 6, d = nL & 63;
            #pragma unroll
            for (int i = 0; i < 4; ++i) {
                const int mb = m0 + wm + i * 16 + l4 * 4;
                #pragma unroll
                for (int r = 0; r < 4; ++r) {
                    const int m = mb + r;
                    const int b = m >> 10, s = m & 1023;
                    O[(((size_t)b * Hh + hh) * Ss + s) * DH + d] = f2b(acc[i][j][r] + bs);
                }
            }
        }
    } else {
        #pragma unroll
        for (int j = 0; j < 4; ++j) {
            const int nL = n0 + wn + j * 16 + l15 - 2 * Dd;
            const float bs = bias[nL];
            const int hh = nL >> 6, d = nL & 63;
            #pragma unroll
            for (int i = 0; i < 4; ++i) {
                const int m = m0 + wm + i * 16 + l4 * 4;
                const int b = m >> 10, s = m & 1023;
                ushort4 o;
                o.x = f2b(acc[i][j][0] + bs);
                o.y = f2b(acc[i][j][1] + bs);
                o.z = f2b(acc[i][j][2] + bs);
                o.w = f2b(acc[i][j][3] + bs);
                *reinterpret_cast<ushort4*>(Vo + (((size_t)b * Hh + hh) * DH + d) * Ss + s) = o;
            }
        }
    }
}

// ---------------- kernel 3: flash attention (unchanged from R5 — verified) ----------------
__global__ __launch_bounds__(256) void k_attn(
    const unsigned short* __restrict__ Q,   // [96][1024][64]
    const unsigned short* __restrict__ K,   // [96][1024][64]
    const unsigned short* __restrict__ VT,  // [96][64][1024]
    const float* __restrict__ mask,         // [8][1024]
    float* __restrict__ out) {              // [8][1024][768]
    __shared__ __align__(16) unsigned short Kl[64 * 64];   // swizzled [row][slot^row&7]
    __shared__ __align__(16) unsigned short Vl[64 * 64];   // swizzled
    __shared__ __align__(16) unsigned short Pl[4][16][72];
    __shared__ __align__(16) float Ml[1024];               // mask * log2e

    const int bid = blockIdx.x;                 // 0..1535
    const int wg  = (bid & 7) * 192 + (bid >> 3);
    const int bh  = wg >> 4;                    // 16 consecutive wg share a head
    const int qt  = wg & 15;
    const int b = bh / Hh, h = bh % Hh;
    const int tid = threadIdx.x, lane = tid & 63, wv = tid >> 6;
    const int l15 = lane & 15, l4 = lane >> 4;
    const int q0 = qt * 64 + wv * 16;

    const unsigned short* Qb = Q + (size_t)bh * Ss * DH;
    const unsigned short* Kb = K + (size_t)bh * Ss * DH;
    const unsigned short* Vb = VT + (size_t)bh * DH * Ss;
    const float* mb = mask + (size_t)b * Ss;

    {
        const float4 mv = *reinterpret_cast<const float4*>(mb + tid * 4);
        float4 ms;
        ms.x = mv.x * 1.44269504f; ms.y = mv.y * 1.44269504f;
        ms.z = mv.z * 1.44269504f; ms.w = mv.w * 1.44269504f;
        *reinterpret_cast<float4*>(&Ml[tid * 4]) = ms;
    }

    const bf16x8 qf0 = *reinterpret_cast<const bf16x8*>(Qb + (q0 + l15) * DH + l4 * 8);
    const bf16x8 qf1 = *reinterpret_cast<const bf16x8*>(Qb + (q0 + l15) * DH + 32 + l4 * 8);

    float m2 = -3.0e38f, lsum = 0.f;
    f32x4 oacc[4];
    #pragma unroll
    for (int dt = 0; dt < 4; ++dt) oacc[dt] = f32x4{0.f, 0.f, 0.f, 0.f};

    const float C1 = 0.125f * 1.44269504f;

    const int srow = lane >> 3;
    const int sslt = lane & 7;

    for (int kt = 0; kt < Ss / 64; ++kt) {
        {
            const int r0 = wv * 16;
            #pragma unroll
            for (int i = 0; i < 2; ++i) {
                const int rK = r0 + i * 8 + srow;
                const int gsK = sslt ^ (rK & 7);
                gll16(Kb + (size_t)(kt * 64 + rK) * DH + gsK * 8, Kl + (r0 + i * 8) * 64);
                gll16(Vb + (size_t)rK * Ss + kt * 64 + gsK * 8,   Vl + (r0 + i * 8) * 64);
            }
        }
        __syncthreads();

        f32x4 sc[4];
        #pragma unroll
        for (int ct = 0; ct < 4; ++ct) {
            const int kr = ct * 16 + l15;
            const int sw = kr & 7;
            const bf16x8 kf0 = *reinterpret_cast<const bf16x8*>(Kl + kr * 64 + ((l4 ^ sw) * 8));
            const bf16x8 kf1 = *reinterpret_cast<const bf16x8*>(Kl + kr * 64 + (((l4 + 4) ^ sw) * 8));
            f32x4 a = f32x4{0.f, 0.f, 0.f, 0.f};
            a = __builtin_amdgcn_mfma_f32_16x16x32_bf16(kf0, qf0, a, 0, 0, 0);
            a = __builtin_amdgcn_mfma_f32_16x16x32_bf16(kf1, qf1, a, 0, 0, 0);
            sc[ct] = a;
        }

        float4 mk[4];
        #pragma unroll
        for (int ct = 0; ct < 4; ++ct)
            mk[ct] = *reinterpret_cast<const float4*>(&Ml[kt * 64 + ct * 16 + l4 * 4]);

        float p[16];
        float pmax = -3.0e38f;
        const bool dk = (kt == qt);
        #pragma unroll
        for (int ct = 0; ct < 4; ++ct) {
            const float* mkp = reinterpret_cast<const float*>(&mk[ct]);
            #pragma unroll
            for (int r = 0; r < 4; ++r) {
                float t = fmaf(sc[ct][r], C1, mkp[r]);
                if (dk && (ct * 16 + l4 * 4 + r) == (wv * 16 + l15)) t = mkp[r];
                p[ct * 4 + r] = t;
                pmax = fmaxf(pmax, t);
            }
        }
        pmax = fmaxf(pmax, __shfl_xor(pmax, 16));
        pmax = fmaxf(pmax, __shfl_xor(pmax, 32));

        if (__any(pmax > m2 + 10.f)) {
            const float mnew = fmaxf(m2, pmax);
            const float alpha = __builtin_amdgcn_exp2f(m2 - mnew);
            m2 = mnew;
            lsum *= alpha;
            float ar[4];
            #pragma unroll
            for (int r = 0; r < 4; ++r) ar[r] = __shfl(alpha, l4 * 4 + r);
            #pragma unroll
            for (int dt = 0; dt < 4; ++dt)
                #pragma unroll
                for (int r = 0; r < 4; ++r) oacc[dt][r] *= ar[r];
        }

        float rs = 0.f;
        #pragma unroll
        for (int i = 0; i < 16; ++i) {
            const float e = __builtin_amdgcn_exp2f(p[i] - m2);
            p[i] = e;
            rs += e;
        }
        rs += __shfl_xor(rs, 16);
        rs += __shfl_xor(rs, 32);
        lsum += rs;

        #pragma unroll
        for (int ct = 0; ct < 4; ++ct) {
            unsigned lo, hi;
            asm("v_cvt_pk_bf16_f32 %0, %1, %2" : "=v"(lo) : "v"(p[ct * 4 + 0]), "v"(p[ct * 4 + 1]));
            asm("v_cvt_pk_bf16_f32 %0, %1, %2" : "=v"(hi) : "v"(p[ct * 4 + 2]), "v"(p[ct * 4 + 3]));
            *reinterpret_cast<uint2*>(&Pl[wv][l15][ct * 16 + l4 * 4]) = make_uint2(lo, hi);
        }

        const bf16x8 pf0 = *reinterpret_cast<const bf16x8*>(&Pl[wv][l15][l4 * 8]);
        const bf16x8 pf1 = *reinterpret_cast<const bf16x8*>(&Pl[wv][l15][32 + l4 * 8]);
        #pragma unroll
        for (int dt = 0; dt < 4; ++dt) {
            const int vr = dt * 16 + l15;
            const int sv = vr & 7;
            const bf16x8 vf0 = *reinterpret_cast<const bf16x8*>(Vl + vr * 64 + ((l4 ^ sv) * 8));
            const bf16x8 vf1 = *reinterpret_cast<const bf16x8*>(Vl + vr * 64 + (((l4 + 4) ^ sv) * 8));
            oacc[dt] = __builtin_amdgcn_mfma_f32_16x16x32_bf16(pf0, vf0, oacc[dt], 0, 0, 0);
            oacc[dt] = __builtin_amdgcn_mfma_f32_16x16x32_bf16(pf1, vf1, oacc[dt], 0, 0, 0);
        }
        __syncthreads();
    }

    #pragma unroll
    for (int r = 0; r < 4; ++r) {
        const float li = __shfl(lsum, l4 * 4 + r);
        const float inv = 1.f / li;
        const int s = qt * 64 + wv * 16 + l4 * 4 + r;
        float* op = out + ((size_t)b * Ss + s) * Dd + h * DH;
        #pragma unroll
        for (int dt = 0; dt < 4; ++dt)
            op[dt * 16 + l15] = oacc[dt][r] * inv;
    }
}

extern "C" void kernel_launch(void* const* d_in, const int* in_sizes, int n_in,
                              void* d_out, int out_size, void* d_ws, size_t ws_size,
                              hipStream_t stream) {
    const float* hs   = (const float*)d_in[0];
    const float* mask = (const float*)d_in[1];
    const float* Wq   = (const float*)d_in[2];
    const float* bq   = (const float*)d_in[3];
    const float* Wk   = (const float*)d_in[4];
    const float* bk   = (const float*)d_in[5];
    const float* Wv   = (const float*)d_in[6];
    const float* bv   = (const float*)d_in[7];
    float* out = (float*)d_out;

    uint8_t* ws = (uint8_t*)d_ws;
    unsigned short* hb = (unsigned short*)(ws);
    unsigned short* Wt = (unsigned short*)(ws + 12582912);
    unsigned short* Qw = (unsigned short*)(ws + 16121856);
    unsigned short* Kw = (unsigned short*)(ws + 28704768);
    unsigned short* Vw = (unsigned short*)(ws + 41287680);

    hipLaunchKernelGGL(k_prep, dim3(7873), dim3(256), 0, stream,
                       hs, Wq, Wk, Wv, mask, hb, Wt, out + 6291456);
    hipLaunchKernelGGL(k_qkv,  dim3(1152), dim3(256), 0, stream,
                       hb, Wt, bq, bk, bv, Qw, Kw, Vw);
    hipLaunchKernelGGL(k_attn, dim3(1536), dim3(256), 0, stream, Qw, Kw, Vw, mask, out);
}